// Round 1
// baseline (308.564 us; speedup 1.0000x reference)
//
#include <hip/hip_runtime.h>

// Problem constants
#define HS 256
#define W3 768              // 3*H
#define CCH 56              // C = C_FEAT + N_PARTS
#define CF 32               // C_FEAT
#define NP 24               // N_PARTS
#define NPTS 8192
#define PLANE_SZ (HS * W3)  // 196608 floats per (b, c) slab

// Kernel A: M[b, y, x3] = mean over c in [0,32) of triplane[b, c, y, x3]
// Grid: (B*PLANE_SZ/4) / 256 blocks of 256 threads; float4 per thread.
__global__ void tp_mean_kernel(const float* __restrict__ tri,
                               float* __restrict__ M) {
    int i4 = blockIdx.x * blockDim.x + threadIdx.x;     // [0, 4*49152)
    int b = i4 / (PLANE_SZ / 4);
    int rem = i4 % (PLANE_SZ / 4);
    const float4* in = (const float4*)tri + (size_t)b * CCH * (PLANE_SZ / 4) + rem;
    float4 acc = {0.f, 0.f, 0.f, 0.f};
#pragma unroll
    for (int c = 0; c < CF; ++c) {
        float4 v = in[(size_t)c * (PLANE_SZ / 4)];
        acc.x += v.x; acc.y += v.y; acc.z += v.z; acc.w += v.w;
    }
    const float s = 1.0f / (float)CF;
    acc.x *= s; acc.y *= s; acc.z *= s; acc.w *= s;
    ((float4*)M)[(size_t)b * (PLANE_SZ / 4) + rem] = acc;
}

// Kernel B: one thread per (point, part). Block = 192 threads = 8 points x 24 parts.
__global__ __launch_bounds__(192) void tp_sample_kernel(
    const float* __restrict__ tri, const float* __restrict__ coords,
    const int* __restrict__ index, const float* __restrict__ M,
    float* __restrict__ out) {
    __shared__ float s_feat[8][NP];
    __shared__ float s_log[8][NP];

    const int tid = threadIdx.x;
    const int lp = tid / NP;    // local point 0..7
    const int part = tid % NP;  // 0..23
    const int point = blockIdx.x * 8 + lp;  // b*NPTS + n, [0, 32768)
    const int b = point >> 13;              // / NPTS

    const int idx = index[point];
    const int row = idx * NP + part;
    const float x = coords[row * 3 + 0];
    const float y = coords[row * 3 + 1];
    const float z = coords[row * 3 + 2];

    // plane 0: (x,y); plane 1: (x,z); plane 2: (y,z)  (u->width, v->height)
    const float us[3] = {x, x, y};
    const float vs[3] = {y, z, z};

    const float* __restrict__ Mb = M + (size_t)b * PLANE_SZ;
    const float* __restrict__ Tb = tri + (size_t)(b * CCH + CF + part) * PLANE_SZ;

    float feat = 0.f, lg = 0.f;
#pragma unroll
    for (int k = 0; k < 3; ++k) {
        const float px = (us[k] + 1.0f) * (HS * 0.5f) - 0.5f;
        const float py = (vs[k] + 1.0f) * (HS * 0.5f) - 0.5f;
        const float x0f = floorf(px);
        const float y0f = floorf(py);
        const float wx = px - x0f;
        const float wy = py - y0f;
        const int x0 = min(max((int)x0f, 0), HS - 1);
        const int x1 = min(max((int)x0f + 1, 0), HS - 1);
        const int y0 = min(max((int)y0f, 0), HS - 1);
        const int y1 = min(max((int)y0f + 1, 0), HS - 1);
        const float w00 = (1.f - wx) * (1.f - wy);
        const float w01 = wx * (1.f - wy);
        const float w10 = (1.f - wx) * wy;
        const float w11 = wx * wy;
        const int o00 = y0 * W3 + k * HS + x0;
        const int o01 = y0 * W3 + k * HS + x1;
        const int o10 = y1 * W3 + k * HS + x0;
        const int o11 = y1 * W3 + k * HS + x1;
        feat += Mb[o00] * w00 + Mb[o01] * w01 + Mb[o10] * w10 + Mb[o11] * w11;
        lg   += Tb[o00] * w00 + Tb[o01] * w01 + Tb[o10] * w10 + Tb[o11] * w11;
    }

    s_feat[lp][part] = feat;
    s_log[lp][part] = lg;
    __syncthreads();

    if (tid < 8) {
        float mx = -1e30f;
#pragma unroll
        for (int j = 0; j < NP; ++j) mx = fmaxf(mx, s_log[tid][j]);
        float se = 0.f, acc = 0.f;
#pragma unroll
        for (int j = 0; j < NP; ++j) {
            const float e = __expf(s_log[tid][j] - mx);
            se += e;
            acc += e * s_feat[tid][j];
        }
        out[blockIdx.x * 8 + tid] = acc / se;
    }
}

extern "C" void kernel_launch(void* const* d_in, const int* in_sizes, int n_in,
                              void* d_out, int out_size, void* d_ws, size_t ws_size,
                              hipStream_t stream) {
    const float* tri = (const float*)d_in[0];
    const float* coords = (const float*)d_in[1];
    const int* index = (const int*)d_in[2];
    float* out = (float*)d_out;
    float* M = (float*)d_ws;  // B * PLANE_SZ floats = 3,145,728 B

    // Kernel A: B*PLANE_SZ/4 = 196608 float4 elements; 256 threads/block
    tp_mean_kernel<<<(4 * PLANE_SZ / 4) / 256, 256, 0, stream>>>(tri, M);

    // Kernel B: 32768 points / 8 per block = 4096 blocks of 192 threads
    tp_sample_kernel<<<4096, 192, 0, stream>>>(tri, coords, index, M, out);
}